// Round 13
// baseline (112.495 us; speedup 1.0000x reference)
//
#include <hip/hip_runtime.h>

#define NBINS   1024
#define CAPC    4096
#define TARGETC 256
#define DET     100
#define XCLIP   4.135166556742356f
#define CHUNK   24
#define TILE4   576    // 546 used float4 slots + clamp pad

__device__ inline float scalar_to_float(const int* p) {
  int v = *p;
  return (v >= 0 && v < (1 << 20)) ? (float)v : __int_as_float(v);
}

struct Box { float x1, y1, x2, y2; };

__device__ inline Box decode_clip(float4 r, float4 p, float W, float H) {
  float w = p.z - p.x, h = p.w - p.y;
  float cx = p.x + 0.5f * w, cy = p.y + 0.5f * h;
  float dx = r.x / 10.f, dy = r.y / 10.f;
  float dw = fminf(r.z / 5.f, XCLIP), dh = fminf(r.w / 5.f, XCLIP);
  float pcx = dx * w + cx, pcy = dy * h + cy;
  float pw = __expf(dw) * w, ph = __expf(dh) * h;
  Box b;
  b.x1 = fminf(fmaxf(pcx - 0.5f * pw, 0.f), W);
  b.y1 = fminf(fmaxf(pcy - 0.5f * ph, 0.f), H);
  b.x2 = fminf(fmaxf(pcx + 0.5f * pw, 0.f), W);
  b.y2 = fminf(fmaxf(pcy + 0.5f * ph, 0.f), H);
  return b;
}

__device__ inline float iou_f(const Box& a, const Box& b) {
  float area1 = (a.x2 - a.x1) * (a.y2 - a.y1);
  float area2 = (b.x2 - b.x1) * (b.y2 - b.y1);
  float lx = fmaxf(a.x1, b.x1), ly = fmaxf(a.y1, b.y1);
  float rx = fminf(a.x2, b.x2), ry = fminf(a.y2, b.y2);
  float w = fmaxf(rx - lx, 0.f), h = fmaxf(ry - ly, 0.f);
  float inter = w * h;
  return inter / (area1 + area2 - inter);
}

// K0: zero the global histogram.
__global__ __launch_bounds__(1024) void k0_zero(unsigned int* __restrict__ hist) {
  hist[threadIdx.x] = 0u;
}

// K1 v12: v11 skeleton (global_load_lds double-buffer, 7 blocks/CU) + LDS
// histogram with one atomic flush per block (R3-proven).
__global__ __launch_bounds__(256) void k1_score(
    const float* __restrict__ logits, const float* __restrict__ reg,
    const float* __restrict__ prop, const int* __restrict__ ph,
    const int* __restrict__ pw, float* __restrict__ scores,
    int* __restrict__ labels, unsigned int* __restrict__ hist, int N) {
  __shared__ float4 tile[2][TILE4];       // 18432 B
  __shared__ unsigned int lh[NBINS];      // 4096 B
  const int t = threadIdx.x, wv = t >> 6, lane = t & 63;
  for (int i = t; i < NBINS; i += 256) lh[i] = 0u;
  const float W = scalar_to_float(pw), H = scalar_to_float(ph);
  const int nchunks = (N + CHUNK - 1) / CHUNK;

  auto stage = [&](int cc, int b) {
    const int rows = min(CHUNK, N - cc * CHUNK);
    const int nf = rows * 91, nf4 = nf >> 2;
    const float4* s4 = (const float4*)(logits + (size_t)cc * CHUNK * 91);
    float4* dst = &tile[b][0];
    #pragma unroll
    for (int k = 0; k < 3; ++k) {
      int b4 = (wv + (k << 2)) << 6;      // load L = wv+4k, wave-uniform base
      if (b4 < nf4) {
        int g = b4 + lane;
        if (g > nf4 - 1) g = nf4 - 1;     // clamped dups land in pad slots
        __builtin_amdgcn_global_load_lds(
            (const __attribute__((address_space(1))) void*)(s4 + g),
            (__attribute__((address_space(3))) void*)(dst + b4),
            16, 0, 0);
      }
    }
    for (int i = (nf4 << 2) + t; i < nf; i += 256)   // generic-N tail only
      ((float*)dst)[i] = logits[(size_t)cc * CHUNK * 91 + i];
  };

  int c = blockIdx.x;
  int cur = 0;
  if (c < nchunks) stage(c, 0);
  __syncthreads();    // also covers lh init
  while (c < nchunks) {
    const int cn = c + gridDim.x;
    if (cn < nchunks) stage(cn, cur ^ 1);  // in flight during compute below
    const int rows = min(CHUNK, N - c * CHUNK);
    const int r = t >> 3, s = t & 7;
    if (r < rows) {
      const float* rowp = (const float*)&tile[cur][0] + r * 91;
      float mv = -3.402823466e38f; int mi = 1 << 20;
      float e0 = 0.f, e1 = 0.f;
      #pragma unroll
      for (int k = 0; k < 12; ++k) {
        int j = s + (k << 3);
        if (j < 91) {
          float v = rowp[j];
          float ex = __expf(v);
          if (k & 1) e1 += ex; else e0 += ex;
          if (v > mv) { mv = v; mi = j; }
        }
      }
      float e = e0 + e1;
      #pragma unroll
      for (int m = 1; m <= 4; m <<= 1) {
        float ov = __shfl_xor(mv, m, 64);
        int   oi = __shfl_xor(mi, m, 64);
        float oe = __shfl_xor(e, m, 64);
        e += oe;
        if (ov > mv || (ov == mv && oi < mi)) { mv = ov; mi = oi; }
      }
      if (s == 0) {
        float top1 = __expf(mv) / e;
        const int row = c * CHUNK + r;
        float4 rg = ((const float4*)reg)[row];
        float4 pp = ((const float4*)prop)[row];
        Box b = decode_clip(rg, pp, W, H);
        bool valid = (top1 > 0.05f) && ((b.x2 - b.x1) >= 0.01f) && ((b.y2 - b.y1) >= 0.01f);
        float sc = valid ? top1 : -1.f;
        scores[row] = sc;
        labels[row] = mi;
        if (sc > 0.f) {
          int bin = (int)(sc * (float)NBINS);
          if (bin > NBINS - 1) bin = NBINS - 1;
          atomicAdd(&lh[bin], 1u);
        }
      }
    }
    __syncthreads();   // drains staging vmcnt AFTER compute
    cur ^= 1;
    c = cn;
  }
  __syncthreads();
  for (int i = t; i < NBINS; i += 256) {
    unsigned int cu = lh[i];
    if (cu) atomicAdd(&hist[i], cu);
  }
}

// K_tail: one block, 1024 threads. Cutoff from hist -> float4 compaction of
// scores straight into LDS keys (LDS atomic append) -> bitonic sort over
// next-pow2(count) -> chunked greedy NMS -> output.
__global__ __launch_bounds__(1024) void k_tail(
    const float* __restrict__ scores, const unsigned int* __restrict__ hist,
    const float* __restrict__ reg, const float* __restrict__ prop,
    const int* __restrict__ labels, const int* __restrict__ ph,
    const int* __restrict__ pw, float* __restrict__ out, int N) {
  __shared__ unsigned long long keys[CAPC];
  __shared__ unsigned int wsum[16];
  __shared__ unsigned int wtail[16];
  __shared__ int bstar;
  __shared__ unsigned int ccount;
  __shared__ Box kbox[DET];
  __shared__ int klab[DET];
  __shared__ float kscore[DET];
  __shared__ Box cbox[64];
  __shared__ int clab[64];
  __shared__ float cscore[64];
  __shared__ unsigned int supk[64];
  __shared__ unsigned int rowm[64][2];
  __shared__ int nkept;
  const int t = threadIdx.x;
  const int lane = t & 63, w = t >> 6;
  // ---- 1) cutoff: suffix scan over hist ----
  const unsigned int h0 = hist[t];
  unsigned int v = h0;
  #pragma unroll
  for (int m = 1; m < 64; m <<= 1) {
    unsigned int o = __shfl_down(v, m, 64);
    if (lane + m < 64) v += o;
  }
  if (lane == 0) wsum[w] = v;
  if (t == 0) { bstar = 0; ccount = 0u; nkept = 0; }
  __syncthreads();
  if (w == 0) {
    unsigned int u = (lane < 16) ? wsum[lane] : 0u;
    unsigned int inc = u;
    #pragma unroll
    for (int m = 1; m < 16; m <<= 1) {
      unsigned int o = __shfl_down(inc, m, 64);
      if (lane + m < 16) inc += o;
    }
    if (lane < 16) wtail[lane] = inc - u;
  }
  __syncthreads();
  unsigned int St = v + wtail[w];
  unsigned int St1 = St - h0;
  if (St >= TARGETC && St1 < TARGETC) {
    int b = t;
    if (St > CAPC) b = t + 1;
    if (b > NBINS - 1) b = NBINS - 1;
    bstar = b;
  }
  __syncthreads();
  const int bs = bstar;
  // ---- 2) compaction into LDS keys ----
  auto consider = [&](float sc, int idx) {
    if (sc > 0.f) {
      int bin = (int)(sc * (float)NBINS);
      if (bin > NBINS - 1) bin = NBINS - 1;
      if (bin >= bs) {
        unsigned int pos = atomicAdd(&ccount, 1u);
        if (pos < CAPC)
          keys[pos] = ((unsigned long long)__float_as_uint(sc) << 32) |
                      (unsigned long long)(0xFFFFFFFFu - (unsigned int)idx);
      }
    }
  };
  const int n4 = N >> 2;
  const float4* s4 = (const float4*)scores;
  for (int i = t; i < n4; i += 1024) {
    float4 q = s4[i];
    consider(q.x, 4 * i + 0);
    consider(q.y, 4 * i + 1);
    consider(q.z, 4 * i + 2);
    consider(q.w, 4 * i + 3);
  }
  for (int i = (n4 << 2) + t; i < N; i += 1024) consider(scores[i], i);
  __syncthreads();
  int count = (ccount < (unsigned int)CAPC) ? (int)ccount : CAPC;
  int P = 1;
  while (P < count) P <<= 1;
  if (P < 2) P = 2;
  for (int i = count + t; i < P; i += 1024) keys[i] = 0ULL;
  __syncthreads();
  // ---- 3) bitonic sort, descending ----
  for (int k = 2; k <= P; k <<= 1) {
    for (int j = k >> 1; j > 0; j >>= 1) {
      for (int i = t; i < P; i += 1024) {
        int ixj = i ^ j;
        if (ixj > i) {
          unsigned long long a = keys[i], b = keys[ixj];
          bool sw = ((i & k) == 0) ? (a < b) : (a > b);
          if (sw) { keys[i] = b; keys[ixj] = a; }
        }
      }
      __syncthreads();
    }
  }
  // ---- 4) chunked greedy NMS ----
  const float W = scalar_to_float(pw), H = scalar_to_float(ph);
  for (int base = 0; base < count && nkept < DET; base += 64) {
    int nc = count - base; if (nc > 64) nc = 64;
    if (t < 64) { supk[t] = 0u; rowm[t][0] = 0u; rowm[t][1] = 0u; }
    if (t < nc) {
      unsigned long long key = keys[base + t];
      int row = (int)(0xFFFFFFFFu - (unsigned int)(key & 0xFFFFFFFFULL));
      cscore[t] = __uint_as_float((unsigned int)(key >> 32));
      clab[t] = labels[row];
      float4 r = ((const float4*)reg)[row];
      float4 p = ((const float4*)prop)[row];
      cbox[t] = decode_clip(r, p, W, H);
    }
    __syncthreads();
    int nk = nkept;
    {
      int c = t >> 4, kk = t & 15;
      if (c < nc) {
        unsigned int hit = 0u;
        for (int j = kk; j < nk; j += 16) {
          if (clab[c] == klab[j] && iou_f(cbox[c], kbox[j]) > 0.5f) { hit = 1u; break; }
        }
        if (hit) atomicOr(&supk[c], 1u);
      }
    }
    for (int p4 = t; p4 < 64 * 64; p4 += 1024) {
      int a = p4 >> 6, b = p4 & 63;
      if (a < b && b < nc) {
        if (clab[a] == clab[b] && iou_f(cbox[a], cbox[b]) > 0.5f)
          atomicOr(&rowm[a][b >> 5], 1u << (b & 31));
      }
    }
    __syncthreads();
    if (t == 0) {
      unsigned int s0 = 0u, s1 = 0u;
      int nkl = nkept;
      for (int j = 0; j < nc && nkl < DET; ++j) {
        unsigned int bit = (j < 32) ? ((s0 >> j) & 1u) : ((s1 >> (j - 32)) & 1u);
        if (!supk[j] && !bit) {
          kbox[nkl] = cbox[j];
          klab[nkl] = clab[j];
          kscore[nkl] = cscore[j];
          ++nkl;
          s0 |= rowm[j][0];
          s1 |= rowm[j][1];
        }
      }
      nkept = nkl;
    }
    __syncthreads();
  }
  // ---- 5) output ----
  int nk = nkept;
  if (t < DET) {
    bool vld = t < nk;
    Box b = vld ? kbox[t] : Box{0.f, 0.f, 0.f, 0.f};
    out[t * 4 + 0] = b.x1;
    out[t * 4 + 1] = b.y1;
    out[t * 4 + 2] = b.x2;
    out[t * 4 + 3] = b.y2;
    out[400 + t] = vld ? kscore[t] : 0.f;
    out[500 + t] = vld ? (float)klab[t] : -1.f;
  }
}

extern "C" void kernel_launch(void* const* d_in, const int* in_sizes, int n_in,
                              void* d_out, int out_size, void* d_ws, size_t ws_size,
                              hipStream_t stream) {
  const float* logits = (const float*)d_in[0];
  const float* reg    = (const float*)d_in[1];
  const float* prop   = (const float*)d_in[2];
  const int*   ph     = (const int*)d_in[3];
  const int*   pw     = (const int*)d_in[4];
  float* out = (float*)d_out;

  const int N = in_sizes[1] / 4;

  char* ws = (char*)d_ws;
  float* scores = (float*)ws;                                  // N f32
  int* labels   = (int*)(ws + (size_t)N * 4);                  // N i32
  size_t off = (size_t)N * 8;
  off = (off + 255) & ~(size_t)255;
  unsigned int* hist = (unsigned int*)(ws + off);              // NBINS u32

  k0_zero<<<1, 1024, 0, stream>>>(hist);
  k1_score<<<1792, 256, 0, stream>>>(logits, reg, prop, ph, pw, scores, labels, hist, N);
  k_tail<<<1, 1024, 0, stream>>>(scores, hist, reg, prop, labels, ph, pw, out, N);
}

// Round 14
// 97.355 us; speedup vs baseline: 1.1555x; 1.1555x over previous
//
#include <hip/hip_runtime.h>

#define NBINS   1024
#define CAPC    4096
#define TARGETC 256
#define DET     100
#define XCLIP   4.135166556742356f
#define CHUNK   24
#define TILE4   576    // 546 used float4 slots + clamp pad
#define K2GRID  256

__device__ inline float scalar_to_float(const int* p) {
  int v = *p;
  return (v >= 0 && v < (1 << 20)) ? (float)v : __int_as_float(v);
}

struct Box { float x1, y1, x2, y2; };

__device__ inline Box decode_clip(float4 r, float4 p, float W, float H) {
  float w = p.z - p.x, h = p.w - p.y;
  float cx = p.x + 0.5f * w, cy = p.y + 0.5f * h;
  float dx = r.x / 10.f, dy = r.y / 10.f;
  float dw = fminf(r.z / 5.f, XCLIP), dh = fminf(r.w / 5.f, XCLIP);
  float pcx = dx * w + cx, pcy = dy * h + cy;
  float pw = __expf(dw) * w, ph = __expf(dh) * h;
  Box b;
  b.x1 = fminf(fmaxf(pcx - 0.5f * pw, 0.f), W);
  b.y1 = fminf(fmaxf(pcy - 0.5f * ph, 0.f), H);
  b.x2 = fminf(fmaxf(pcx + 0.5f * pw, 0.f), W);
  b.y2 = fminf(fmaxf(pcy + 0.5f * ph, 0.f), H);
  return b;
}

__device__ inline float iou_f(const Box& a, const Box& b) {
  float area1 = (a.x2 - a.x1) * (a.y2 - a.y1);
  float area2 = (b.x2 - b.x1) * (b.y2 - b.y1);
  float lx = fmaxf(a.x1, b.x1), ly = fmaxf(a.y1, b.y1);
  float rx = fminf(a.x2, b.x2), ry = fminf(a.y2, b.y2);
  float w = fmaxf(rx - lx, 0.f), h = fmaxf(ry - ly, 0.f);
  float inter = w * h;
  return inter / (area1 + area2 - inter);
}

// K0: zero hist + counter + done.
__global__ __launch_bounds__(1024) void k0_zero(unsigned int* __restrict__ hist) {
  const int t = threadIdx.x;
  hist[t] = 0u;
  if (t < 64) hist[NBINS + t] = 0u;   // counter @ NBINS, done @ NBINS+16
}

// K1 v12: global_load_lds double-buffer (7 blocks/CU, 28 waves/CU) + LDS
// histogram with one atomic flush per block.
__global__ __launch_bounds__(256) void k1_score(
    const float* __restrict__ logits, const float* __restrict__ reg,
    const float* __restrict__ prop, const int* __restrict__ ph,
    const int* __restrict__ pw, float* __restrict__ scores,
    int* __restrict__ labels, unsigned int* __restrict__ hist, int N) {
  __shared__ float4 tile[2][TILE4];       // 18432 B
  __shared__ unsigned int lh[NBINS];      // 4096 B
  const int t = threadIdx.x, wv = t >> 6, lane = t & 63;
  for (int i = t; i < NBINS; i += 256) lh[i] = 0u;
  const float W = scalar_to_float(pw), H = scalar_to_float(ph);
  const int nchunks = (N + CHUNK - 1) / CHUNK;

  auto stage = [&](int cc, int b) {
    const int rows = min(CHUNK, N - cc * CHUNK);
    const int nf = rows * 91, nf4 = nf >> 2;
    const float4* s4 = (const float4*)(logits + (size_t)cc * CHUNK * 91);
    float4* dst = &tile[b][0];
    #pragma unroll
    for (int k = 0; k < 3; ++k) {
      int b4 = (wv + (k << 2)) << 6;      // load L = wv+4k, wave-uniform base
      if (b4 < nf4) {
        int g = b4 + lane;
        if (g > nf4 - 1) g = nf4 - 1;     // clamped dups land in pad slots
        __builtin_amdgcn_global_load_lds(
            (const __attribute__((address_space(1))) void*)(s4 + g),
            (__attribute__((address_space(3))) void*)(dst + b4),
            16, 0, 0);
      }
    }
    for (int i = (nf4 << 2) + t; i < nf; i += 256)   // generic-N tail only
      ((float*)dst)[i] = logits[(size_t)cc * CHUNK * 91 + i];
  };

  int c = blockIdx.x;
  int cur = 0;
  if (c < nchunks) stage(c, 0);
  __syncthreads();    // also covers lh init
  while (c < nchunks) {
    const int cn = c + gridDim.x;
    if (cn < nchunks) stage(cn, cur ^ 1);  // in flight during compute below
    const int rows = min(CHUNK, N - c * CHUNK);
    const int r = t >> 3, s = t & 7;
    if (r < rows) {
      const float* rowp = (const float*)&tile[cur][0] + r * 91;
      float mv = -3.402823466e38f; int mi = 1 << 20;
      float e0 = 0.f, e1 = 0.f;
      #pragma unroll
      for (int k = 0; k < 12; ++k) {
        int j = s + (k << 3);
        if (j < 91) {
          float v = rowp[j];
          float ex = __expf(v);
          if (k & 1) e1 += ex; else e0 += ex;
          if (v > mv) { mv = v; mi = j; }
        }
      }
      float e = e0 + e1;
      #pragma unroll
      for (int m = 1; m <= 4; m <<= 1) {
        float ov = __shfl_xor(mv, m, 64);
        int   oi = __shfl_xor(mi, m, 64);
        float oe = __shfl_xor(e, m, 64);
        e += oe;
        if (ov > mv || (ov == mv && oi < mi)) { mv = ov; mi = oi; }
      }
      if (s == 0) {
        float top1 = __expf(mv) / e;
        const int row = c * CHUNK + r;
        float4 rg = ((const float4*)reg)[row];
        float4 pp = ((const float4*)prop)[row];
        Box b = decode_clip(rg, pp, W, H);
        bool valid = (top1 > 0.05f) && ((b.x2 - b.x1) >= 0.01f) && ((b.y2 - b.y1) >= 0.01f);
        float sc = valid ? top1 : -1.f;
        scores[row] = sc;
        labels[row] = mi;
        if (sc > 0.f) {
          int bin = (int)(sc * (float)NBINS);
          if (bin > NBINS - 1) bin = NBINS - 1;
          atomicAdd(&lh[bin], 1u);
        }
      }
    }
    __syncthreads();   // drains staging vmcnt AFTER compute
    cur ^= 1;
    c = cn;
  }
  __syncthreads();
  for (int i = t; i < NBINS; i += 256) {
    unsigned int cu = lh[i];
    if (cu) atomicAdd(&hist[i], cu);
  }
}

// K2 fused tail: 256 blocks do cutoff + multi-block compaction (full-BW scan)
// into global cand; device-scope release + done-signal; block 0 alone spins,
// then sorts + NMS at 1024 threads. Only block 0 waits -> no deadlock.
__global__ __launch_bounds__(1024) void k2_fused(
    const float* __restrict__ scores, const unsigned int* __restrict__ hist,
    unsigned long long* __restrict__ cand, unsigned int* __restrict__ counter,
    unsigned int* __restrict__ done,
    const float* __restrict__ reg, const float* __restrict__ prop,
    const int* __restrict__ labels, const int* __restrict__ ph,
    const int* __restrict__ pw, float* __restrict__ out, int N) {
  __shared__ unsigned long long keys[CAPC];
  __shared__ unsigned int wsum[16];
  __shared__ unsigned int wtail[16];
  __shared__ int bstar;
  __shared__ Box kbox[DET];
  __shared__ int klab[DET];
  __shared__ float kscore[DET];
  __shared__ Box cbox[64];
  __shared__ int clab[64];
  __shared__ float cscore[64];
  __shared__ unsigned int supk[64];
  __shared__ unsigned int rowm[64][2];
  __shared__ int nkept;
  const int t = threadIdx.x;
  const int lane = t & 63, w = t >> 6;
  // ---- 1) cutoff (every block, redundant) ----
  const unsigned int h0 = hist[t];
  unsigned int v = h0;
  #pragma unroll
  for (int m = 1; m < 64; m <<= 1) {
    unsigned int o = __shfl_down(v, m, 64);
    if (lane + m < 64) v += o;
  }
  if (lane == 0) wsum[w] = v;
  if (t == 0) { bstar = 0; nkept = 0; }
  __syncthreads();
  if (w == 0) {
    unsigned int u = (lane < 16) ? wsum[lane] : 0u;
    unsigned int inc = u;
    #pragma unroll
    for (int m = 1; m < 16; m <<= 1) {
      unsigned int o = __shfl_down(inc, m, 64);
      if (lane + m < 16) inc += o;
    }
    if (lane < 16) wtail[lane] = inc - u;
  }
  __syncthreads();
  {
    unsigned int St = v + wtail[w];
    unsigned int St1 = St - h0;
    if (St >= TARGETC && St1 < TARGETC) {
      int b = t;
      if (St > CAPC) b = t + 1;
      if (b > NBINS - 1) b = NBINS - 1;
      bstar = b;
    }
  }
  __syncthreads();
  const int bs = bstar;
  // ---- 2) multi-block compaction (each thread <=1 float4 at N=200000) ----
  auto consider = [&](float sc, int idx) {
    if (sc > 0.f) {
      int bin = (int)(sc * (float)NBINS);
      if (bin > NBINS - 1) bin = NBINS - 1;
      if (bin >= bs) {
        unsigned int pos = atomicAdd(counter, 1u);
        if (pos < CAPC) {
          unsigned long long key =
              ((unsigned long long)__float_as_uint(sc) << 32) |
              (unsigned long long)(0xFFFFFFFFu - (unsigned int)idx);
          __hip_atomic_store(&cand[pos], key, __ATOMIC_RELEASE,
                             __HIP_MEMORY_SCOPE_AGENT);
        }
      }
    }
  };
  const int n4 = N >> 2;
  const float4* s4 = (const float4*)scores;
  for (int i = blockIdx.x * 1024 + t; i < n4; i += K2GRID * 1024) {
    float4 q = s4[i];
    consider(q.x, 4 * i + 0);
    consider(q.y, 4 * i + 1);
    consider(q.z, 4 * i + 2);
    consider(q.w, 4 * i + 3);
  }
  for (int i = (n4 << 2) + blockIdx.x * 1024 + t; i < N; i += K2GRID * 1024)
    consider(scores[i], i);
  __syncthreads();
  if (t == 0) {
    __threadfence();                    // release all cand/counter traffic
    atomicAdd(done, 1u);
  }
  if (blockIdx.x != 0) return;
  // ---- 3) block 0: wait for all compaction blocks ----
  if (t == 0) {
    while (__hip_atomic_load(done, __ATOMIC_ACQUIRE, __HIP_MEMORY_SCOPE_AGENT)
           < (unsigned int)K2GRID) { }
  }
  __syncthreads();
  unsigned int cnt_u = __hip_atomic_load(counter, __ATOMIC_ACQUIRE,
                                         __HIP_MEMORY_SCOPE_AGENT);
  int count = (cnt_u < (unsigned int)CAPC) ? (int)cnt_u : CAPC;
  int P = 1;
  while (P < count) P <<= 1;
  if (P < 2) P = 2;
  for (int i = t; i < P; i += 1024)
    keys[i] = (i < count)
        ? __hip_atomic_load(&cand[i], __ATOMIC_RELAXED, __HIP_MEMORY_SCOPE_AGENT)
        : 0ULL;
  __syncthreads();
  // ---- 4) bitonic sort, descending ----
  for (int k = 2; k <= P; k <<= 1) {
    for (int j = k >> 1; j > 0; j >>= 1) {
      for (int i = t; i < P; i += 1024) {
        int ixj = i ^ j;
        if (ixj > i) {
          unsigned long long a = keys[i], b = keys[ixj];
          bool sw = ((i & k) == 0) ? (a < b) : (a > b);
          if (sw) { keys[i] = b; keys[ixj] = a; }
        }
      }
      __syncthreads();
    }
  }
  // ---- 5) chunked greedy NMS ----
  const float W = scalar_to_float(pw), H = scalar_to_float(ph);
  for (int base = 0; base < count && nkept < DET; base += 64) {
    int nc = count - base; if (nc > 64) nc = 64;
    if (t < 64) { supk[t] = 0u; rowm[t][0] = 0u; rowm[t][1] = 0u; }
    if (t < nc) {
      unsigned long long key = keys[base + t];
      int row = (int)(0xFFFFFFFFu - (unsigned int)(key & 0xFFFFFFFFULL));
      cscore[t] = __uint_as_float((unsigned int)(key >> 32));
      clab[t] = labels[row];
      float4 r = ((const float4*)reg)[row];
      float4 p = ((const float4*)prop)[row];
      cbox[t] = decode_clip(r, p, W, H);
    }
    __syncthreads();
    int nk = nkept;
    {
      int c = t >> 4, kk = t & 15;
      if (c < nc) {
        unsigned int hit = 0u;
        for (int j = kk; j < nk; j += 16) {
          if (clab[c] == klab[j] && iou_f(cbox[c], kbox[j]) > 0.5f) { hit = 1u; break; }
        }
        if (hit) atomicOr(&supk[c], 1u);
      }
    }
    for (int p4 = t; p4 < 64 * 64; p4 += 1024) {
      int a = p4 >> 6, b = p4 & 63;
      if (a < b && b < nc) {
        if (clab[a] == clab[b] && iou_f(cbox[a], cbox[b]) > 0.5f)
          atomicOr(&rowm[a][b >> 5], 1u << (b & 31));
      }
    }
    __syncthreads();
    if (t == 0) {
      unsigned int s0 = 0u, s1 = 0u;
      int nkl = nkept;
      for (int j = 0; j < nc && nkl < DET; ++j) {
        unsigned int bit = (j < 32) ? ((s0 >> j) & 1u) : ((s1 >> (j - 32)) & 1u);
        if (!supk[j] && !bit) {
          kbox[nkl] = cbox[j];
          klab[nkl] = clab[j];
          kscore[nkl] = cscore[j];
          ++nkl;
          s0 |= rowm[j][0];
          s1 |= rowm[j][1];
        }
      }
      nkept = nkl;
    }
    __syncthreads();
  }
  // ---- 6) output ----
  int nk = nkept;
  if (t < DET) {
    bool vld = t < nk;
    Box b = vld ? kbox[t] : Box{0.f, 0.f, 0.f, 0.f};
    out[t * 4 + 0] = b.x1;
    out[t * 4 + 1] = b.y1;
    out[t * 4 + 2] = b.x2;
    out[t * 4 + 3] = b.y2;
    out[400 + t] = vld ? kscore[t] : 0.f;
    out[500 + t] = vld ? (float)klab[t] : -1.f;
  }
}

extern "C" void kernel_launch(void* const* d_in, const int* in_sizes, int n_in,
                              void* d_out, int out_size, void* d_ws, size_t ws_size,
                              hipStream_t stream) {
  const float* logits = (const float*)d_in[0];
  const float* reg    = (const float*)d_in[1];
  const float* prop   = (const float*)d_in[2];
  const int*   ph     = (const int*)d_in[3];
  const int*   pw     = (const int*)d_in[4];
  float* out = (float*)d_out;

  const int N = in_sizes[1] / 4;

  char* ws = (char*)d_ws;
  float* scores = (float*)ws;                                  // N f32
  int* labels   = (int*)(ws + (size_t)N * 4);                  // N i32
  size_t off = (size_t)N * 8;
  off = (off + 255) & ~(size_t)255;
  unsigned int* hist = (unsigned int*)(ws + off);              // NBINS u32 (+64 ctl)
  unsigned int* counter = hist + NBINS;                        // 1 u32
  unsigned int* done    = hist + NBINS + 16;                   // 1 u32
  unsigned long long* cand =
      (unsigned long long*)(ws + off + (NBINS + 64) * 4);      // CAPC u64

  k0_zero<<<1, 1024, 0, stream>>>(hist);
  k1_score<<<1792, 256, 0, stream>>>(logits, reg, prop, ph, pw, scores, labels, hist, N);
  k2_fused<<<K2GRID, 1024, 0, stream>>>(scores, hist, cand, counter, done,
                                        reg, prop, labels, ph, pw, out, N);
}

// Round 15
// 67.949 us; speedup vs baseline: 1.6556x; 1.4328x over previous
//
#include <hip/hip_runtime.h>

#define NBINS   1024
#define CAPC    4096
#define TARGETC 256
#define DET     100
#define XCLIP   4.135166556742356f
#define CHUNK   24
#define TILE4   576    // 546 used float4 slots + clamp pad
#define K2GRID  64     // 1 block/CU -> guaranteed co-resident

__device__ inline float scalar_to_float(const int* p) {
  int v = *p;
  return (v >= 0 && v < (1 << 20)) ? (float)v : __int_as_float(v);
}

struct Box { float x1, y1, x2, y2; };

__device__ inline Box decode_clip(float4 r, float4 p, float W, float H) {
  float w = p.z - p.x, h = p.w - p.y;
  float cx = p.x + 0.5f * w, cy = p.y + 0.5f * h;
  float dx = r.x / 10.f, dy = r.y / 10.f;
  float dw = fminf(r.z / 5.f, XCLIP), dh = fminf(r.w / 5.f, XCLIP);
  float pcx = dx * w + cx, pcy = dy * h + cy;
  float pw = __expf(dw) * w, ph = __expf(dh) * h;
  Box b;
  b.x1 = fminf(fmaxf(pcx - 0.5f * pw, 0.f), W);
  b.y1 = fminf(fmaxf(pcy - 0.5f * ph, 0.f), H);
  b.x2 = fminf(fmaxf(pcx + 0.5f * pw, 0.f), W);
  b.y2 = fminf(fmaxf(pcy + 0.5f * ph, 0.f), H);
  return b;
}

__device__ inline float iou_f(const Box& a, const Box& b) {
  float area1 = (a.x2 - a.x1) * (a.y2 - a.y1);
  float area2 = (b.x2 - b.x1) * (b.y2 - b.y1);
  float lx = fmaxf(a.x1, b.x1), ly = fmaxf(a.y1, b.y1);
  float rx = fminf(a.x2, b.x2), ry = fminf(a.y2, b.y2);
  float w = fmaxf(rx - lx, 0.f), h = fmaxf(ry - ly, 0.f);
  float inter = w * h;
  return inter / (area1 + area2 - inter);
}

// K1 = R11 no-hist kernel: global_load_lds double-buffer, 8 blocks/CU,
// 32 waves/CU. Block 0 zeroes the 3 control words (stream order covers k2).
__global__ __launch_bounds__(256) void k1_score(
    const float* __restrict__ logits, const float* __restrict__ reg,
    const float* __restrict__ prop, const int* __restrict__ ph,
    const int* __restrict__ pw, float* __restrict__ scores,
    int* __restrict__ labels, unsigned int* __restrict__ ctl, int N) {
  __shared__ float4 tile[2][TILE4];       // 18432 B
  const int t = threadIdx.x, wv = t >> 6, lane = t & 63;
  if (blockIdx.x == 0 && t < 3) ctl[t * 16] = 0u;   // counter, done1, done2
  const float W = scalar_to_float(pw), H = scalar_to_float(ph);
  const int nchunks = (N + CHUNK - 1) / CHUNK;

  auto stage = [&](int cc, int b) {
    const int rows = min(CHUNK, N - cc * CHUNK);
    const int nf = rows * 91, nf4 = nf >> 2;
    const float4* s4 = (const float4*)(logits + (size_t)cc * CHUNK * 91);
    float4* dst = &tile[b][0];
    #pragma unroll
    for (int k = 0; k < 3; ++k) {
      int b4 = (wv + (k << 2)) << 6;      // load L = wv+4k, wave-uniform base
      if (b4 < nf4) {
        int g = b4 + lane;
        if (g > nf4 - 1) g = nf4 - 1;     // clamped dups land in pad slots
        __builtin_amdgcn_global_load_lds(
            (const __attribute__((address_space(1))) void*)(s4 + g),
            (__attribute__((address_space(3))) void*)(dst + b4),
            16, 0, 0);
      }
    }
    for (int i = (nf4 << 2) + t; i < nf; i += 256)   // generic-N tail only
      ((float*)dst)[i] = logits[(size_t)cc * CHUNK * 91 + i];
  };

  int c = blockIdx.x;
  int cur = 0;
  if (c < nchunks) stage(c, 0);
  __syncthreads();
  while (c < nchunks) {
    const int cn = c + gridDim.x;
    if (cn < nchunks) stage(cn, cur ^ 1);  // in flight during compute below
    const int rows = min(CHUNK, N - c * CHUNK);
    const int r = t >> 3, s = t & 7;
    if (r < rows) {
      const float* rowp = (const float*)&tile[cur][0] + r * 91;
      float mv = -3.402823466e38f; int mi = 1 << 20;
      float e0 = 0.f, e1 = 0.f;
      #pragma unroll
      for (int k = 0; k < 12; ++k) {
        int j = s + (k << 3);
        if (j < 91) {
          float v = rowp[j];
          float ex = __expf(v);
          if (k & 1) e1 += ex; else e0 += ex;
          if (v > mv) { mv = v; mi = j; }
        }
      }
      float e = e0 + e1;
      #pragma unroll
      for (int m = 1; m <= 4; m <<= 1) {
        float ov = __shfl_xor(mv, m, 64);
        int   oi = __shfl_xor(mi, m, 64);
        float oe = __shfl_xor(e, m, 64);
        e += oe;
        if (ov > mv || (ov == mv && oi < mi)) { mv = ov; mi = oi; }
      }
      if (s == 0) {
        float top1 = __expf(mv) / e;
        const int row = c * CHUNK + r;
        float4 rg = ((const float4*)reg)[row];
        float4 pp = ((const float4*)prop)[row];
        Box b = decode_clip(rg, pp, W, H);
        bool valid = (top1 > 0.05f) && ((b.x2 - b.x1) >= 0.01f) && ((b.y2 - b.y1) >= 0.01f);
        float sc = valid ? top1 : -1.f;
        scores[row] = sc;
        labels[row] = mi;
      }
    }
    __syncthreads();   // drains staging vmcnt AFTER compute
    cur ^= 1;
    c = cn;
  }
}

// K2 all-in-one tail, 64 co-resident blocks:
//  A) per-block LDS hist -> histp partials -> fence -> done1
//  B) all blocks spin(done1==64) -> sum partials -> suffix scan -> cutoff
//  C) grid-stride compaction -> cand (release) -> fence -> done2; blocks!=0 exit
//  D) block 0 spin(done2==64) -> LDS bitonic sort -> greedy NMS -> output
__global__ __launch_bounds__(1024) void k2_allinone(
    const float* __restrict__ scores, unsigned int* __restrict__ histp,
    unsigned long long* __restrict__ cand, unsigned int* __restrict__ ctl,
    const float* __restrict__ reg, const float* __restrict__ prop,
    const int* __restrict__ labels, const int* __restrict__ ph,
    const int* __restrict__ pw, float* __restrict__ out, int N) {
  __shared__ unsigned long long keys[CAPC];
  __shared__ unsigned int lh[NBINS];
  __shared__ unsigned int wsum[16];
  __shared__ unsigned int wtail[16];
  __shared__ int bstar;
  __shared__ Box kbox[DET];
  __shared__ int klab[DET];
  __shared__ float kscore[DET];
  __shared__ Box cbox[64];
  __shared__ int clab[64];
  __shared__ float cscore[64];
  __shared__ unsigned int supk[64];
  __shared__ unsigned int rowm[64][2];
  __shared__ int nkept;
  unsigned int* counter = ctl;
  unsigned int* done1 = ctl + 16;
  unsigned int* done2 = ctl + 32;
  const int t = threadIdx.x;
  const int lane = t & 63, w = t >> 6;
  const int n4 = N >> 2;
  const float4* s4 = (const float4*)scores;
  // ---- A) per-block histogram ----
  lh[t] = 0u;
  if (t == 0) { bstar = 0; nkept = 0; }
  __syncthreads();
  for (int i = blockIdx.x * 1024 + t; i < n4; i += K2GRID * 1024) {
    float4 q = s4[i];
    #pragma unroll
    for (int e = 0; e < 4; ++e) {
      float sc = (e == 0) ? q.x : (e == 1) ? q.y : (e == 2) ? q.z : q.w;
      if (sc > 0.f) {
        int bin = (int)(sc * (float)NBINS);
        if (bin > NBINS - 1) bin = NBINS - 1;
        atomicAdd(&lh[bin], 1u);
      }
    }
  }
  for (int i = (n4 << 2) + blockIdx.x * 1024 + t; i < N; i += K2GRID * 1024) {
    float sc = scores[i];
    if (sc > 0.f) {
      int bin = (int)(sc * (float)NBINS);
      if (bin > NBINS - 1) bin = NBINS - 1;
      atomicAdd(&lh[bin], 1u);
    }
  }
  __syncthreads();
  histp[blockIdx.x * NBINS + t] = lh[t];
  __syncthreads();            // all stores complete (vmcnt drained)
  if (t == 0) {
    __threadfence();          // flush to device scope
    atomicAdd(done1, 1u);
    while (__hip_atomic_load(done1, __ATOMIC_ACQUIRE, __HIP_MEMORY_SCOPE_AGENT)
           < (unsigned int)K2GRID) { }
  }
  __syncthreads();
  // ---- B) cutoff ----
  unsigned int h0 = 0u;
  #pragma unroll 8
  for (int b = 0; b < K2GRID; ++b) h0 += histp[b * NBINS + t];
  unsigned int v = h0;
  #pragma unroll
  for (int m = 1; m < 64; m <<= 1) {
    unsigned int o = __shfl_down(v, m, 64);
    if (lane + m < 64) v += o;
  }
  if (lane == 0) wsum[w] = v;
  __syncthreads();
  if (w == 0) {
    unsigned int u = (lane < 16) ? wsum[lane] : 0u;
    unsigned int inc = u;
    #pragma unroll
    for (int m = 1; m < 16; m <<= 1) {
      unsigned int o = __shfl_down(inc, m, 64);
      if (lane + m < 16) inc += o;
    }
    if (lane < 16) wtail[lane] = inc - u;
  }
  __syncthreads();
  {
    unsigned int St = v + wtail[w];
    unsigned int St1 = St - h0;
    if (St >= TARGETC && St1 < TARGETC) {
      int b = t;
      if (St > CAPC) b = t + 1;
      if (b > NBINS - 1) b = NBINS - 1;
      bstar = b;
    }
  }
  __syncthreads();
  const int bs = bstar;
  // ---- C) compaction ----
  auto consider = [&](float sc, int idx) {
    if (sc > 0.f) {
      int bin = (int)(sc * (float)NBINS);
      if (bin > NBINS - 1) bin = NBINS - 1;
      if (bin >= bs) {
        unsigned int pos = atomicAdd(counter, 1u);
        if (pos < CAPC) {
          unsigned long long key =
              ((unsigned long long)__float_as_uint(sc) << 32) |
              (unsigned long long)(0xFFFFFFFFu - (unsigned int)idx);
          __hip_atomic_store(&cand[pos], key, __ATOMIC_RELEASE,
                             __HIP_MEMORY_SCOPE_AGENT);
        }
      }
    }
  };
  for (int i = blockIdx.x * 1024 + t; i < n4; i += K2GRID * 1024) {
    float4 q = s4[i];
    consider(q.x, 4 * i + 0);
    consider(q.y, 4 * i + 1);
    consider(q.z, 4 * i + 2);
    consider(q.w, 4 * i + 3);
  }
  for (int i = (n4 << 2) + blockIdx.x * 1024 + t; i < N; i += K2GRID * 1024)
    consider(scores[i], i);
  __syncthreads();
  if (t == 0) {
    __threadfence();
    atomicAdd(done2, 1u);
  }
  if (blockIdx.x != 0) return;
  // ---- D) block 0: sort + NMS ----
  if (t == 0) {
    while (__hip_atomic_load(done2, __ATOMIC_ACQUIRE, __HIP_MEMORY_SCOPE_AGENT)
           < (unsigned int)K2GRID) { }
  }
  __syncthreads();
  unsigned int cnt_u = __hip_atomic_load(counter, __ATOMIC_ACQUIRE,
                                         __HIP_MEMORY_SCOPE_AGENT);
  int count = (cnt_u < (unsigned int)CAPC) ? (int)cnt_u : CAPC;
  int P = 1;
  while (P < count) P <<= 1;
  if (P < 2) P = 2;
  for (int i = t; i < P; i += 1024)
    keys[i] = (i < count)
        ? __hip_atomic_load(&cand[i], __ATOMIC_RELAXED, __HIP_MEMORY_SCOPE_AGENT)
        : 0ULL;
  __syncthreads();
  for (int k = 2; k <= P; k <<= 1) {
    for (int j = k >> 1; j > 0; j >>= 1) {
      for (int i = t; i < P; i += 1024) {
        int ixj = i ^ j;
        if (ixj > i) {
          unsigned long long a = keys[i], b = keys[ixj];
          bool sw = ((i & k) == 0) ? (a < b) : (a > b);
          if (sw) { keys[i] = b; keys[ixj] = a; }
        }
      }
      __syncthreads();
    }
  }
  const float W = scalar_to_float(pw), H = scalar_to_float(ph);
  for (int base = 0; base < count && nkept < DET; base += 64) {
    int nc = count - base; if (nc > 64) nc = 64;
    if (t < 64) { supk[t] = 0u; rowm[t][0] = 0u; rowm[t][1] = 0u; }
    if (t < nc) {
      unsigned long long key = keys[base + t];
      int row = (int)(0xFFFFFFFFu - (unsigned int)(key & 0xFFFFFFFFULL));
      cscore[t] = __uint_as_float((unsigned int)(key >> 32));
      clab[t] = labels[row];
      float4 r = ((const float4*)reg)[row];
      float4 p = ((const float4*)prop)[row];
      cbox[t] = decode_clip(r, p, W, H);
    }
    __syncthreads();
    int nk = nkept;
    {
      int c = t >> 4, kk = t & 15;
      if (c < nc) {
        unsigned int hit = 0u;
        for (int j = kk; j < nk; j += 16) {
          if (clab[c] == klab[j] && iou_f(cbox[c], kbox[j]) > 0.5f) { hit = 1u; break; }
        }
        if (hit) atomicOr(&supk[c], 1u);
      }
    }
    for (int p4 = t; p4 < 64 * 64; p4 += 1024) {
      int a = p4 >> 6, b = p4 & 63;
      if (a < b && b < nc) {
        if (clab[a] == clab[b] && iou_f(cbox[a], cbox[b]) > 0.5f)
          atomicOr(&rowm[a][b >> 5], 1u << (b & 31));
      }
    }
    __syncthreads();
    if (t == 0) {
      unsigned int s0 = 0u, s1 = 0u;
      int nkl = nkept;
      for (int j = 0; j < nc && nkl < DET; ++j) {
        unsigned int bit = (j < 32) ? ((s0 >> j) & 1u) : ((s1 >> (j - 32)) & 1u);
        if (!supk[j] && !bit) {
          kbox[nkl] = cbox[j];
          klab[nkl] = clab[j];
          kscore[nkl] = cscore[j];
          ++nkl;
          s0 |= rowm[j][0];
          s1 |= rowm[j][1];
        }
      }
      nkept = nkl;
    }
    __syncthreads();
  }
  int nk = nkept;
  if (t < DET) {
    bool vld = t < nk;
    Box b = vld ? kbox[t] : Box{0.f, 0.f, 0.f, 0.f};
    out[t * 4 + 0] = b.x1;
    out[t * 4 + 1] = b.y1;
    out[t * 4 + 2] = b.x2;
    out[t * 4 + 3] = b.y2;
    out[400 + t] = vld ? kscore[t] : 0.f;
    out[500 + t] = vld ? (float)klab[t] : -1.f;
  }
}

extern "C" void kernel_launch(void* const* d_in, const int* in_sizes, int n_in,
                              void* d_out, int out_size, void* d_ws, size_t ws_size,
                              hipStream_t stream) {
  const float* logits = (const float*)d_in[0];
  const float* reg    = (const float*)d_in[1];
  const float* prop   = (const float*)d_in[2];
  const int*   ph     = (const int*)d_in[3];
  const int*   pw     = (const int*)d_in[4];
  float* out = (float*)d_out;

  const int N = in_sizes[1] / 4;

  char* ws = (char*)d_ws;
  float* scores = (float*)ws;                                  // N f32
  int* labels   = (int*)(ws + (size_t)N * 4);                  // N i32
  size_t off = (size_t)N * 8;
  off = (off + 255) & ~(size_t)255;
  unsigned int* ctl = (unsigned int*)(ws + off);               // 64 u32 control
  unsigned int* histp = ctl + 64;                              // K2GRID*NBINS u32
  unsigned long long* cand =
      (unsigned long long*)(ws + off + (64 + K2GRID * NBINS) * 4 + 64);

  k1_score<<<2048, 256, 0, stream>>>(logits, reg, prop, ph, pw, scores, labels, ctl, N);
  k2_allinone<<<K2GRID, 1024, 0, stream>>>(scores, histp, cand, ctl,
                                           reg, prop, labels, ph, pw, out, N);
}